// Round 10
// baseline (197.984 us; speedup 1.0000x reference)
//
#include <hip/hip_runtime.h>
#include <cstdint>

constexpr int N_FEAT  = 8;
constexpr int E_FEAT  = 4;
constexpr int NUM_IN  = 2 * (N_FEAT + 2) + E_FEAT + 1;  // 25
constexpr int NUM_OUT = 2 * N_FEAT + E_FEAT;            // 20
constexpr int BLK     = 256;
constexpr int RS      = 32;   // fp16 LDS row stride: 32 halves = 64 B = 4 x b128

// Evidence trail (dispatch-us / VALUBusy / VGPR):
//   SMEM weights EPT=1:        77 / 40% / 52  -- lgkmcnt(0) drain convoys
//   VMEM weights EPT=1:       171 / 19% / 80  -- no pipelining of 281 loads
//   LDS fp32 EPT=1 (R6 mold):  70 / 44% / 64  -- LDS bus: 315 bcast b128 x ~8cy
//       x 4 waves = 10080 LDS-cy vs 4500 SIMD-cy FMA -> predicted VALU 45% ✓
//   EPT=2 (5 forms):          spills, 3.5-3.8 GB scratch -- allocator refuses
//   fp16 flat + (4,8):         88 / 36% / 32  -- attr chased 8 waves/EU, rolled
//       loops + scratch; mechanism untested.
// This round: fp16 weights INSIDE the proven R6 mold (EPT=1, per-row unrolled,
// scalar acc, constant indices, waves_per_eu(3,4)). 180 bcast reads/edge
// (vs 315) -> LDS-cy/round ~5760 vs 4500 FMA-cy -> ~40 us if v_fma_mix fuses,
// ~47 us if cvt is separate. fp16 weights passed the harness in R9.

typedef _Float16 half8 __attribute__((ext_vector_type(8)));  // 16 B = 1 ds_read_b128

__global__ __launch_bounds__(BLK)
__attribute__((amdgpu_waves_per_eu(3, 4)))
void edge_mlp(
    const float* __restrict__ r,
    const float* __restrict__ a_data,
    const float* __restrict__ a_mat,
    const float* __restrict__ a_inf,
    const float* __restrict__ b_data,
    const float* __restrict__ b_mat,
    const float* __restrict__ b_inf,
    const float* __restrict__ e_data,
    const float* __restrict__ W1,   // (25,25) row-major fp32
    const float* __restrict__ B1,   // (25,)
    const float* __restrict__ W2,   // (20,25) row-major
    const float* __restrict__ B2,   // (20,)
    float*       __restrict__ out,  // fp32, 3 segments concatenated
    int E) {
  __shared__ __align__(16) _Float16 sW1h[NUM_IN  * RS];  // 800 halves, 1.6 KB
  __shared__ __align__(16) _Float16 sW2h[NUM_OUT * RS];  // 640 halves, 1.28 KB

  const int tid = threadIdx.x;
  // ---- stage fp16 weights, rows padded to 32 halves; pad = 0, single pass ----
  for (int i = tid; i < NUM_IN * RS; i += BLK) {
    const int row = i / RS, col = i % RS;
    sW1h[i] = (col < NUM_IN) ? (_Float16)W1[row * NUM_IN + col] : (_Float16)0.f;
  }
  for (int i = tid; i < NUM_OUT * RS; i += BLK) {
    const int row = i / RS, col = i % RS;
    sW2h[i] = (col < NUM_IN) ? (_Float16)W2[row * NUM_IN + col] : (_Float16)0.f;
  }
  __syncthreads();

  const int e = blockIdx.x * BLK + tid;
  if (e >= E) return;

  // ---- gather the 25 fp32 input features (proven-promoting form) ----
  const float4* a4 = reinterpret_cast<const float4*>(a_data) + 2 * (size_t)e;
  const float4* b4 = reinterpret_cast<const float4*>(b_data) + 2 * (size_t)e;
  float4 a0 = a4[0], a1 = a4[1];
  float4 b0 = b4[0], b1v = b4[1];
  float4 ev = reinterpret_cast<const float4*>(e_data)[e];

  float x[NUM_IN];
  x[0]  = r[e];
  x[1]  = a0.x; x[2]  = a0.y; x[3]  = a0.z; x[4]  = a0.w;
  x[5]  = a1.x; x[6]  = a1.y; x[7]  = a1.z; x[8]  = a1.w;
  x[9]  = a_mat[e];
  x[10] = a_inf[e];
  x[11] = b0.x; x[12] = b0.y; x[13] = b0.z; x[14] = b0.w;
  x[15] = b1v.x; x[16] = b1v.y; x[17] = b1v.z; x[18] = b1v.w;
  x[19] = b_mat[e];
  x[20] = b_inf[e];
  x[21] = ev.x; x[22] = ev.y; x[23] = ev.z; x[24] = ev.w;

  const half8* w1v = reinterpret_cast<const half8*>(sW1h);
  const half8* w2v = reinterpret_cast<const half8*>(sW2h);

  // ---- layer 1: per-row, 4 broadcast b128 reads, scalar acc (R6 mold) ----
  float h[NUM_IN];
#pragma unroll
  for (int j = 0; j < NUM_IN; ++j) {
    const half8 q0 = w1v[j * 4 + 0], q1 = w1v[j * 4 + 1];
    const half8 q2 = w1v[j * 4 + 2], q3 = w1v[j * 4 + 3];
    float acc = B1[j];                       // uniform scalar load, hoisted
#pragma unroll
    for (int k = 0; k < NUM_IN; ++k) {       // constant k -> folds
      const _Float16 wv = (k < 8) ? q0[k] : (k < 16) ? q1[k - 8]
                        : (k < 24) ? q2[k - 16] : q3[0];
      acc = fmaf((float)wv, x[k], acc);
    }
    h[j] = fmaxf(acc, 0.0f);
  }

  // ---- layer 2 ----
  float y[NUM_OUT];
#pragma unroll
  for (int j = 0; j < NUM_OUT; ++j) {
    const half8 q0 = w2v[j * 4 + 0], q1 = w2v[j * 4 + 1];
    const half8 q2 = w2v[j * 4 + 2], q3 = w2v[j * 4 + 3];
    float acc = B2[j];
#pragma unroll
    for (int k = 0; k < NUM_IN; ++k) {
      const _Float16 wv = (k < 8) ? q0[k] : (k < 16) ? q1[k - 8]
                        : (k < 24) ? q2[k - 16] : q3[0];
      acc = fmaf((float)wv, h[k], acc);
    }
    y[j] = fmaxf(acc, 0.0f);
  }

  // ---- store fp32 into the 3 concatenated output segments ----
  float4* o0 = reinterpret_cast<float4*>(out) + 2 * (size_t)e;            // (E,8)
  o0[0] = make_float4(y[0], y[1], y[2],  y[3]);
  o0[1] = make_float4(y[4], y[5], y[6],  y[7]);
  float4* o1 = reinterpret_cast<float4*>(out + (size_t)8 * E) + 2 * (size_t)e;  // (E,8)
  o1[0] = make_float4(y[8],  y[9],  y[10], y[11]);
  o1[1] = make_float4(y[12], y[13], y[14], y[15]);
  reinterpret_cast<float4*>(out + (size_t)16 * E)[e] =                    // (E,4)
      make_float4(y[16], y[17], y[18], y[19]);
}

extern "C" void kernel_launch(void* const* d_in, const int* in_sizes, int n_in,
                              void* d_out, int out_size, void* d_ws, size_t ws_size,
                              hipStream_t stream) {
  const float* r      = (const float*)d_in[0];
  const float* a_data = (const float*)d_in[1];
  const float* a_mat  = (const float*)d_in[2];
  const float* a_inf  = (const float*)d_in[3];
  const float* b_data = (const float*)d_in[4];
  const float* b_mat  = (const float*)d_in[5];
  const float* b_inf  = (const float*)d_in[6];
  const float* e_data = (const float*)d_in[7];
  const float* W1     = (const float*)d_in[8];
  const float* B1     = (const float*)d_in[9];
  const float* W2     = (const float*)d_in[10];
  const float* B2     = (const float*)d_in[11];
  int E = in_sizes[0];

  edge_mlp<<<(E + BLK - 1) / BLK, BLK, 0, stream>>>(
      r, a_data, a_mat, a_inf, b_data, b_mat, b_inf, e_data,
      W1, B1, W2, B2, (float*)d_out, E);
}

// Round 11
// 197.248 us; speedup vs baseline: 1.0037x; 1.0037x over previous
//
#include <hip/hip_runtime.h>
#include <cstdint>

constexpr int N_FEAT  = 8;
constexpr int E_FEAT  = 4;
constexpr int NUM_IN  = 2 * (N_FEAT + 2) + E_FEAT + 1;  // 25
constexpr int NUM_OUT = 2 * N_FEAT + E_FEAT;            // 20
constexpr int BLK     = 256;   // 4 waves; 256 edges per block
constexpr int RS      = 40;    // LDS row stride in halves (80 B) -> bank-spread

// MFMA rewrite. Evidence that forced it (dispatch-us / VALUBusy):
//   SMEM fp32 weights: 77/40% ; LDS fp32: 70/44% ; LDS fp16 (half the
//   reads): 70/46%. Three pipes, two widths, same time -> the VALU-FMA
//   path has a ~70us structural floor (latency-chained row accumulation,
//   ~2.8 waves/SIMD), and EPT=2 is allocator-vetoed (6 attempts).
// This kernel feeds the MATRIX pipe instead: per 16-edge tile,
//   L1: C[16e,32n] = X[16e,32k] @ W1^T   (2 x mfma_f32_16x16x32_f16)
//   L2: Y[16e,32n] = H[16e,32k] @ W2^T   (2 x)
// 16 MFMAs/wave per 64 edges (~80cy matrix issue vs 2250cy VALU).
// Verified layouts (cdna4 guide): C/D col=lane&15, row=(lane>>4)*4+reg.
// A/B operand: row/col=lane&15, k = 8*(lane>>4)+i (contiguous-8, per the
// ref-checked m92/m97 bf16x8 row-load GEMMs). Bias enters via C-init
// (bias is lane-uniform in the C layout). h is relu'd -> fp16 -> written
// IN PLACE over its own tile's dead X rows (same wave, in-order DS pipe,
// no barrier needed); only one __syncthreads (weight staging).

typedef _Float16 f16x8 __attribute__((ext_vector_type(8)));
typedef float    f32x4 __attribute__((ext_vector_type(4)));

__global__ __launch_bounds__(BLK)
__attribute__((amdgpu_waves_per_eu(3, 4)))
void edge_mlp(
    const float* __restrict__ r,
    const float* __restrict__ a_data,
    const float* __restrict__ a_mat,
    const float* __restrict__ a_inf,
    const float* __restrict__ b_data,
    const float* __restrict__ b_mat,
    const float* __restrict__ b_inf,
    const float* __restrict__ e_data,
    const float* __restrict__ W1,   // (25,25) row-major fp32
    const float* __restrict__ B1,   // (25,)
    const float* __restrict__ W2,   // (20,25) row-major
    const float* __restrict__ B2,   // (20,)
    float*       __restrict__ out,  // fp32, 3 segments concatenated
    int E) {
  __shared__ __align__(16) _Float16 sX[BLK * RS];   // 20 KB; h overwrites in place
  __shared__ __align__(16) _Float16 sW1[32 * 32];   // 2 KB  [out j][k], zero-padded
  __shared__ __align__(16) _Float16 sW2[32 * 32];   // 2 KB
  __shared__ float sB1[32];
  __shared__ float sB2[32];

  const int tid = threadIdx.x;

  // ---- stage weights (fp16, zero-padded 32x32) + biases ----
  for (int i = tid; i < 1024; i += BLK) {
    const int row = i >> 5, col = i & 31;
    sW1[i] = (row < NUM_IN  && col < NUM_IN) ? (_Float16)W1[row * NUM_IN + col]
                                             : (_Float16)0.f;
    sW2[i] = (row < NUM_OUT && col < NUM_IN) ? (_Float16)W2[row * NUM_IN + col]
                                             : (_Float16)0.f;
  }
  if (tid < 32) {
    sB1[tid] = (tid < NUM_IN)  ? B1[tid] : 0.f;
    sB2[tid] = (tid < NUM_OUT) ? B2[tid] : 0.f;
  }

  // ---- gather this thread's edge (proven coalesced float4 path) -> fp16 ----
  const int ebase = blockIdx.x * BLK;
  int eg = ebase + tid;
  if (eg >= E) eg = E - 1;          // clamp for loads; stores are guarded
  const float4* a4 = reinterpret_cast<const float4*>(a_data) + 2 * (size_t)eg;
  const float4* b4 = reinterpret_cast<const float4*>(b_data) + 2 * (size_t)eg;
  const float4 a0 = a4[0], a1 = a4[1];
  const float4 b0 = b4[0], b1v = b4[1];
  const float4 ev = reinterpret_cast<const float4*>(e_data)[eg];
  const float rv = r[eg], am = a_mat[eg], ai = a_inf[eg];
  const float bm = b_mat[eg], bi = b_inf[eg];

  f16x8 p0, p1, p2, p3;
  p0[0] = (_Float16)rv;    p0[1] = (_Float16)a0.x;  p0[2] = (_Float16)a0.y;
  p0[3] = (_Float16)a0.z;  p0[4] = (_Float16)a0.w;  p0[5] = (_Float16)a1.x;
  p0[6] = (_Float16)a1.y;  p0[7] = (_Float16)a1.z;
  p1[0] = (_Float16)a1.w;  p1[1] = (_Float16)am;    p1[2] = (_Float16)ai;
  p1[3] = (_Float16)b0.x;  p1[4] = (_Float16)b0.y;  p1[5] = (_Float16)b0.z;
  p1[6] = (_Float16)b0.w;  p1[7] = (_Float16)b1v.x;
  p2[0] = (_Float16)b1v.y; p2[1] = (_Float16)b1v.z; p2[2] = (_Float16)b1v.w;
  p2[3] = (_Float16)bm;    p2[4] = (_Float16)bi;    p2[5] = (_Float16)ev.x;
  p2[6] = (_Float16)ev.y;  p2[7] = (_Float16)ev.z;
  p3 = (f16x8)(_Float16)0.f;
  p3[0] = (_Float16)ev.w;

  _Float16* xrow = &sX[tid * RS];
  *reinterpret_cast<f16x8*>(xrow + 0)  = p0;
  *reinterpret_cast<f16x8*>(xrow + 8)  = p1;
  *reinterpret_cast<f16x8*>(xrow + 16) = p2;
  *reinterpret_cast<f16x8*>(xrow + 24) = p3;

  __syncthreads();   // weights/biases visible (sX rows are wave-local)

  // ---- per-wave constants & weight fragments (read once, held in regs) ----
  const int lane = tid & 63;
  const int lr   = lane & 15;          // fragment row (A) / col (B,C)
  const int lk   = (lane >> 4) * 8;    // k-octet base
  const int rg   = (lane >> 4) * 4;    // C/D row-group base
  const int wid  = tid >> 6;

  const f16x8 w1a = *reinterpret_cast<const f16x8*>(&sW1[lr * 32 + lk]);
  const f16x8 w1b = *reinterpret_cast<const f16x8*>(&sW1[(16 + lr) * 32 + lk]);
  const f16x8 w2a = *reinterpret_cast<const f16x8*>(&sW2[lr * 32 + lk]);
  const f16x8 w2b = *reinterpret_cast<const f16x8*>(&sW2[(16 + lr) * 32 + lk]);
  const float b1a = sB1[lr], b1b = sB1[16 + lr];
  const float b2a = sB2[lr], b2b = sB2[16 + lr];

  // per-lane output column pointers (D col = lane&15)
  const size_t E8 = (size_t)E * 8;
  float* yp0 = (lr < 8) ? (out + lr) : (out + E8 + (lr - 8));  // seg0/seg1, stride 8
  float* yp1 = out + 2 * E8 + lr;                              // seg2, stride 4, lr<4

#pragma unroll
  for (int t = 0; t < 4; ++t) {
    const int rb = wid * 64 + t * 16;   // tile's row base within block

    // ---- layer 1: C = X @ W1^T + b1 ----
    const f16x8 xa = *reinterpret_cast<const f16x8*>(&sX[(rb + lr) * RS + lk]);
    f32x4 c0 = {b1a, b1a, b1a, b1a};
    f32x4 c1 = {b1b, b1b, b1b, b1b};
    c0 = __builtin_amdgcn_mfma_f32_16x16x32_f16(xa, w1a, c0, 0, 0, 0);
    c1 = __builtin_amdgcn_mfma_f32_16x16x32_f16(xa, w1b, c1, 0, 0, 0);

    // ---- relu -> fp16 -> in-place over this tile's dead X rows ----
    // lane holds col (lr | 16+lr), rows rb+rg+q. Cols 25-31 come from
    // zero-padded W1 rows + zero bias -> write 0s (keeps k-pad clean for L2).
#pragma unroll
    for (int q = 0; q < 4; ++q) {
      const int hr = rb + rg + q;
      sX[hr * RS + lr]      = (_Float16)fmaxf(c0[q], 0.f);
      sX[hr * RS + 16 + lr] = (_Float16)fmaxf(c1[q], 0.f);
    }

    // ---- layer 2: D = H @ W2^T + b2 (reads rows just written; in-order DS) ----
    const f16x8 ha = *reinterpret_cast<const f16x8*>(&sX[(rb + lr) * RS + lk]);
    f32x4 d0 = {b2a, b2a, b2a, b2a};
    f32x4 d1 = {b2b, b2b, b2b, b2b};
    d0 = __builtin_amdgcn_mfma_f32_16x16x32_f16(ha, w2a, d0, 0, 0, 0);
    d1 = __builtin_amdgcn_mfma_f32_16x16x32_f16(ha, w2b, d1, 0, 0, 0);

    // ---- store: lane = output col, 4 edge-rows per lane-group ----
#pragma unroll
    for (int q = 0; q < 4; ++q) {
      const int grow = ebase + rb + rg + q;
      if (grow < E) {
        yp0[(size_t)grow * 8] = fmaxf(d0[q], 0.f);
        if (lr < 4) yp1[(size_t)grow * 4] = fmaxf(d1[q], 0.f);
      }
    }
  }
}

extern "C" void kernel_launch(void* const* d_in, const int* in_sizes, int n_in,
                              void* d_out, int out_size, void* d_ws, size_t ws_size,
                              hipStream_t stream) {
  const float* r      = (const float*)d_in[0];
  const float* a_data = (const float*)d_in[1];
  const float* a_mat  = (const float*)d_in[2];
  const float* a_inf  = (const float*)d_in[3];
  const float* b_data = (const float*)d_in[4];
  const float* b_mat  = (const float*)d_in[5];
  const float* b_inf  = (const float*)d_in[6];
  const float* e_data = (const float*)d_in[7];
  const float* W1     = (const float*)d_in[8];
  const float* B1     = (const float*)d_in[9];
  const float* W2     = (const float*)d_in[10];
  const float* B2     = (const float*)d_in[11];
  int E = in_sizes[0];

  edge_mlp<<<(E + BLK - 1) / BLK, BLK, 0, stream>>>(
      r, a_data, a_mat, a_inf, b_data, b_mat, b_inf, e_data,
      W1, B1, W2, B2, (float*)d_out, E);
}

// Round 12
// 195.983 us; speedup vs baseline: 1.0102x; 1.0065x over previous
//
#include <hip/hip_runtime.h>
#include <cstdint>

constexpr int N_FEAT  = 8;
constexpr int E_FEAT  = 4;
constexpr int NUM_IN  = 2 * (N_FEAT + 2) + E_FEAT + 1;  // 25
constexpr int NUM_OUT = 2 * N_FEAT + E_FEAT;            // 20
constexpr int BLK     = 256;   // 4 waves; 256 edges per block
constexpr int RS      = 40;    // LDS row stride in halves = 80 B = 20 fp32

// R11 result: MFMA path correct (MfmaUtil 2.3%) but dur stuck at ~67us --
// same as the VALU kernels (70/69). All compute pipes near-idle, HBM at
// ~2 TB/s, occupancy 35% -> the session-long ~68us wall is memory
// latency/inefficiency, not issue throughput. R11's specific sins:
//   (a) 32 scattered single-dword global stores per thread (MFMA lane=col
//       layout) vs the proven 5 x float4 per edge;
//   (b) waves_per_eu(3,4) capping occupancy at ~11 waves/CU.
// This round: stage y through LDS (reusing sX -- row stride 80 B = exactly
// 20 fp32, overwriting the dead X/H bytes of the same wave's rows; in-order
// DS pipe, no barrier) so every thread stores its own edge as 5 x float4;
// and waves_per_eu(6,8) to double TLP (LDS 25KB -> 6 blocks/CU -> 24 waves).

typedef _Float16 f16x8 __attribute__((ext_vector_type(8)));
typedef float    f32x4 __attribute__((ext_vector_type(4)));

__global__ __launch_bounds__(BLK)
__attribute__((amdgpu_waves_per_eu(6, 8)))
void edge_mlp(
    const float* __restrict__ r,
    const float* __restrict__ a_data,
    const float* __restrict__ a_mat,
    const float* __restrict__ a_inf,
    const float* __restrict__ b_data,
    const float* __restrict__ b_mat,
    const float* __restrict__ b_inf,
    const float* __restrict__ e_data,
    const float* __restrict__ W1,   // (25,25) row-major fp32
    const float* __restrict__ B1,   // (25,)
    const float* __restrict__ W2,   // (20,25) row-major
    const float* __restrict__ B2,   // (20,)
    float*       __restrict__ out,  // fp32, 3 segments concatenated
    int E) {
  __shared__ __align__(16) _Float16 sX[BLK * RS];   // 20 KB; X -> H -> y(fp32)
  __shared__ __align__(16) _Float16 sW1[32 * 32];   // 2 KB  [out j][k], zero-pad
  __shared__ __align__(16) _Float16 sW2[32 * 32];   // 2 KB
  __shared__ float sB1[32];
  __shared__ float sB2[32];

  const int tid = threadIdx.x;

  // ---- stage weights (fp16, zero-padded 32x32) + biases ----
  for (int i = tid; i < 1024; i += BLK) {
    const int row = i >> 5, col = i & 31;
    sW1[i] = (row < NUM_IN  && col < NUM_IN) ? (_Float16)W1[row * NUM_IN + col]
                                             : (_Float16)0.f;
    sW2[i] = (row < NUM_OUT && col < NUM_IN) ? (_Float16)W2[row * NUM_IN + col]
                                             : (_Float16)0.f;
  }
  if (tid < 32) {
    sB1[tid] = (tid < NUM_IN)  ? B1[tid] : 0.f;
    sB2[tid] = (tid < NUM_OUT) ? B2[tid] : 0.f;
  }

  // ---- gather this thread's edge (proven coalesced float4 path) -> fp16 ----
  const int ebase = blockIdx.x * BLK;
  int eg = ebase + tid;
  if (eg >= E) eg = E - 1;          // clamp for loads; stores are guarded
  const float4* a4 = reinterpret_cast<const float4*>(a_data) + 2 * (size_t)eg;
  const float4* b4 = reinterpret_cast<const float4*>(b_data) + 2 * (size_t)eg;
  const float4 a0 = a4[0], a1 = a4[1];
  const float4 b0 = b4[0], b1v = b4[1];
  const float4 ev = reinterpret_cast<const float4*>(e_data)[eg];
  const float rv = r[eg], am = a_mat[eg], ai = a_inf[eg];
  const float bm = b_mat[eg], bi = b_inf[eg];

  f16x8 p0, p1, p2, p3;
  p0[0] = (_Float16)rv;    p0[1] = (_Float16)a0.x;  p0[2] = (_Float16)a0.y;
  p0[3] = (_Float16)a0.z;  p0[4] = (_Float16)a0.w;  p0[5] = (_Float16)a1.x;
  p0[6] = (_Float16)a1.y;  p0[7] = (_Float16)a1.z;
  p1[0] = (_Float16)a1.w;  p1[1] = (_Float16)am;    p1[2] = (_Float16)ai;
  p1[3] = (_Float16)b0.x;  p1[4] = (_Float16)b0.y;  p1[5] = (_Float16)b0.z;
  p1[6] = (_Float16)b0.w;  p1[7] = (_Float16)b1v.x;
  p2[0] = (_Float16)b1v.y; p2[1] = (_Float16)b1v.z; p2[2] = (_Float16)b1v.w;
  p2[3] = (_Float16)bm;    p2[4] = (_Float16)bi;    p2[5] = (_Float16)ev.x;
  p2[6] = (_Float16)ev.y;  p2[7] = (_Float16)ev.z;
  p3 = (f16x8)(_Float16)0.f;
  p3[0] = (_Float16)ev.w;

  _Float16* xrow = &sX[tid * RS];
  *reinterpret_cast<f16x8*>(xrow + 0)  = p0;
  *reinterpret_cast<f16x8*>(xrow + 8)  = p1;
  *reinterpret_cast<f16x8*>(xrow + 16) = p2;
  *reinterpret_cast<f16x8*>(xrow + 24) = p3;

  __syncthreads();   // weights/biases visible (sX rows are wave-local)

  // ---- per-wave constants & weight fragments (read once, held in regs) ----
  const int lane = tid & 63;
  const int lr   = lane & 15;          // fragment row (A) / col (B,C)
  const int lk   = (lane >> 4) * 8;    // k-octet base
  const int rg   = (lane >> 4) * 4;    // C/D row-group base
  const int wid  = tid >> 6;

  const f16x8 w1a = *reinterpret_cast<const f16x8*>(&sW1[lr * 32 + lk]);
  const f16x8 w1b = *reinterpret_cast<const f16x8*>(&sW1[(16 + lr) * 32 + lk]);
  const f16x8 w2a = *reinterpret_cast<const f16x8*>(&sW2[lr * 32 + lk]);
  const f16x8 w2b = *reinterpret_cast<const f16x8*>(&sW2[(16 + lr) * 32 + lk]);
  const float b1a = sB1[lr], b1b = sB1[16 + lr];
  const float b2a = sB2[lr], b2b = sB2[16 + lr];

  float* sY = reinterpret_cast<float*>(sX);   // row stride 20 fp32 (= 80 B)

#pragma unroll
  for (int t = 0; t < 4; ++t) {
    const int rb = wid * 64 + t * 16;   // tile's row base within block

    // ---- layer 1: C = X @ W1^T + b1 ----
    const f16x8 xa = *reinterpret_cast<const f16x8*>(&sX[(rb + lr) * RS + lk]);
    f32x4 c0 = {b1a, b1a, b1a, b1a};
    f32x4 c1 = {b1b, b1b, b1b, b1b};
    c0 = __builtin_amdgcn_mfma_f32_16x16x32_f16(xa, w1a, c0, 0, 0, 0);
    c1 = __builtin_amdgcn_mfma_f32_16x16x32_f16(xa, w1b, c1, 0, 0, 0);

    // ---- relu -> fp16 -> in-place over this tile's dead X rows ----
#pragma unroll
    for (int q = 0; q < 4; ++q) {
      const int hr = rb + rg + q;
      sX[hr * RS + lr]      = (_Float16)fmaxf(c0[q], 0.f);
      sX[hr * RS + 16 + lr] = (_Float16)fmaxf(c1[q], 0.f);
    }

    // ---- layer 2: D = H @ W2^T + b2 (in-order DS: reads precede y-write) ----
    const f16x8 ha = *reinterpret_cast<const f16x8*>(&sX[(rb + lr) * RS + lk]);
    f32x4 d0 = {b2a, b2a, b2a, b2a};
    f32x4 d1 = {b2b, b2b, b2b, b2b};
    d0 = __builtin_amdgcn_mfma_f32_16x16x32_f16(ha, w2a, d0, 0, 0, 0);
    d1 = __builtin_amdgcn_mfma_f32_16x16x32_f16(ha, w2b, d1, 0, 0, 0);

    // ---- relu -> y staged in LDS as fp32 over this tile's dead rows ----
#pragma unroll
    for (int q = 0; q < 4; ++q) {
      const int yr = rb + rg + q;
      sY[yr * 20 + lr] = fmaxf(d0[q], 0.f);             // cols 0..15
      if (lr < 4) sY[yr * 20 + 16 + lr] = fmaxf(d1[q], 0.f);  // cols 16..19
    }
  }
  // All rows of this wave (tids wid*64..+63) written by this wave -> in-order
  // DS guarantees visibility to the readback below; no barrier needed.

  // ---- each thread stores its own edge: 5 x float4 (proven coalesced path) ----
  const int e0 = ebase + tid;
  if (e0 < E) {
    const float* yr = sY + tid * 20;
    const float4 v0 = *reinterpret_cast<const float4*>(yr + 0);
    const float4 v1 = *reinterpret_cast<const float4*>(yr + 4);
    const float4 v2 = *reinterpret_cast<const float4*>(yr + 8);
    const float4 v3 = *reinterpret_cast<const float4*>(yr + 12);
    const float4 v4 = *reinterpret_cast<const float4*>(yr + 16);
    float4* o0 = reinterpret_cast<float4*>(out) + 2 * (size_t)e0;           // (E,8)
    o0[0] = v0;
    o0[1] = v1;
    float4* o1 = reinterpret_cast<float4*>(out + (size_t)8 * E) + 2 * (size_t)e0;  // (E,8)
    o1[0] = v2;
    o1[1] = v3;
    reinterpret_cast<float4*>(out + (size_t)16 * E)[e0] = v4;               // (E,4)
  }
}

extern "C" void kernel_launch(void* const* d_in, const int* in_sizes, int n_in,
                              void* d_out, int out_size, void* d_ws, size_t ws_size,
                              hipStream_t stream) {
  const float* r      = (const float*)d_in[0];
  const float* a_data = (const float*)d_in[1];
  const float* a_mat  = (const float*)d_in[2];
  const float* a_inf  = (const float*)d_in[3];
  const float* b_data = (const float*)d_in[4];
  const float* b_mat  = (const float*)d_in[5];
  const float* b_inf  = (const float*)d_in[6];
  const float* e_data = (const float*)d_in[7];
  const float* W1     = (const float*)d_in[8];
  const float* B1     = (const float*)d_in[9];
  const float* W2     = (const float*)d_in[10];
  const float* B2     = (const float*)d_in[11];
  int E = in_sizes[0];

  edge_mlp<<<(E + BLK - 1) / BLK, BLK, 0, stream>>>(
      r, a_data, a_mat, a_inf, b_data, b_mat, b_inf, e_data,
      W1, B1, W2, B2, (float*)d_out, E);
}